// Round 17
// baseline (98.525 us; speedup 1.0000x reference)
//
#include <hip/hip_runtime.h>
#include <hip/hip_bf16.h>

#define BB 2
#define SS 2048
#define DD 1024
#define HH 16
#define DK 64
#define MM (BB*SS)   // 4096

typedef __attribute__((ext_vector_type(8))) short bf16x8;
typedef __attribute__((ext_vector_type(4))) float f32x4;

__device__ inline ushort f2bf(float f) {
  __hip_bfloat16 h = __float2bfloat16(f);
  return *reinterpret_cast<ushort*>(&h);
}

// hardware exp2 (single v_exp_f32)
__device__ __forceinline__ float exp2_hw(float x) {
  float r; asm("v_exp_f32 %0, %1" : "=v"(r) : "v"(x)); return r;
}

// async global->LDS, 16B per lane. ldst must be wave-uniform; HW adds lane*16.
__device__ __forceinline__ void gl_lds16(const ushort* g, ushort* l) {
  __builtin_amdgcn_global_load_lds((const __attribute__((address_space(1))) void*)g,
                                   (__attribute__((address_space(3))) void*)l, 16, 0, 0);
}

// ---------------- fp32 -> bf16 convert (float4 vectorized) ----------------
__global__ void cvt_f32_bf16(const float* __restrict__ src, ushort* __restrict__ dst, int n4) {
  int i = blockIdx.x * blockDim.x + threadIdx.x;
  int stride = gridDim.x * blockDim.x;
  for (int idx = i; idx < n4; idx += stride) {
    float4 v = reinterpret_cast<const float4*>(src)[idx];
    ushort4 o;
    o.x = f2bf(v.x); o.y = f2bf(v.y); o.z = f2bf(v.z); o.w = f2bf(v.w);
    reinterpret_cast<ushort4*>(dst)[idx] = o;
  }
}

// convert 3 weight matrices into one contiguous bf16 buffer
__global__ void cvt3_f32_bf16(const float* __restrict__ s0, const float* __restrict__ s1,
                              const float* __restrict__ s2, ushort* __restrict__ dst) {
  const int n4seg = DD * DD / 4;
  int i = blockIdx.x * blockDim.x + threadIdx.x;
  int stride = gridDim.x * blockDim.x;
  for (int idx = i; idx < 3 * n4seg; idx += stride) {
    int seg = idx / n4seg;
    int off = idx - seg * n4seg;
    const float* s = (seg == 0) ? s0 : (seg == 1) ? s1 : s2;
    float4 v = reinterpret_cast<const float4*>(s)[off];
    ushort4 o;
    o.x = f2bf(v.x); o.y = f2bf(v.y); o.z = f2bf(v.z); o.w = f2bf(v.w);
    reinterpret_cast<ushort4*>(dst)[idx] = o;
  }
}

// one-shot convert: x (MM*DD) -> dx ; wq|wk|wv|wo (4*DD*DD) -> dw contiguous
__global__ void cvt5_f32_bf16(const float* __restrict__ x,
                              const float* __restrict__ s0, const float* __restrict__ s1,
                              const float* __restrict__ s2, const float* __restrict__ s3,
                              ushort* __restrict__ dx, ushort* __restrict__ dw) {
  const int n4x = MM * DD / 4;       // 1M float4
  const int n4seg = DD * DD / 4;     // 256K float4 per weight
  const int total = n4x + 4 * n4seg; // 2M float4
  int i = blockIdx.x * blockDim.x + threadIdx.x;
  int stride = gridDim.x * blockDim.x;
  for (int idx = i; idx < total; idx += stride) {
    float4 v; ushort4* outp;
    if (idx < n4x) {
      v = reinterpret_cast<const float4*>(x)[idx];
      outp = &reinterpret_cast<ushort4*>(dx)[idx];
    } else {
      int widx = idx - n4x;
      int seg = widx / n4seg;
      int off = widx - seg * n4seg;
      const float* s = (seg == 0) ? s0 : (seg == 1) ? s1 : (seg == 2) ? s2 : s3;
      v = reinterpret_cast<const float4*>(s)[off];
      outp = &reinterpret_cast<ushort4*>(dw)[widx];
    }
    ushort4 o;
    o.x = f2bf(v.x); o.y = f2bf(v.y); o.z = f2bf(v.z); o.w = f2bf(v.w);
    *outp = o;
  }
}

// ---------------- fused QKV GEMM: [4096,1024] x [3072,1024]^T ----------------
// 128x128 tile, BK=64, single-buffered 32KB LDS (m97 structure), 3 blocks/CU.
// Epilogue bounces C through the (then-dead) staging LDS for coalesced 16B
// stores: Q/K row-major [row][col]; V transposed [col][row] (s contiguous).
__global__ __launch_bounds__(256, 3) void gemm_qkv(const ushort* __restrict__ A,
                                                   const ushort* __restrict__ Wqkv,
                                                   const float* __restrict__ bq,
                                                   const float* __restrict__ bk,
                                                   const float* __restrict__ bv,
                                                   ushort* __restrict__ Qo,
                                                   ushort* __restrict__ Ko,
                                                   ushort* __restrict__ Vo,
                                                   float qscale) {
  constexpr int K = 1024;
  __shared__ __align__(16) ushort lS[2][128 * 64];   // staging; reused as C-tile
  ushort* lA = lS[0];
  ushort* lB = lS[1];
  const int t = threadIdx.x;
  const int w = t >> 6, lane = t & 63;
  const int flat = blockIdx.x + 24 * blockIdx.y;
  const int xcd = flat & 7, idx = flat >> 3;
  const int m0 = ((xcd << 2) + (idx & 3)) * 128;
  const int n0 = (idx >> 2) * 128;
  const int wm = (w >> 1) * 64, wn = (w & 1) * 64;
  const int c = lane & 15, g = lane >> 4;

  f32x4 acc[4][4];
  #pragma unroll
  for (int i = 0; i < 4; i++)
    #pragma unroll
    for (int j = 0; j < 4; j++) acc[i][j] = f32x4{0.f, 0.f, 0.f, 0.f};

  auto stage = [&](int ks) {
    const int k0 = ks * 64;
    #pragma unroll
    for (int i = 0; i < 4; i++) {
      int ch = w * 256 + i * 64 + lane;
      int row = ch >> 3;
      int cs = (ch & 7) ^ (row & 7);
      gl_lds16(&A[(size_t)(m0 + row) * K + k0 + cs * 8], &lA[(w * 256 + i * 64) * 8]);
      gl_lds16(&Wqkv[(size_t)(n0 + row) * K + k0 + cs * 8], &lB[(w * 256 + i * 64) * 8]);
    }
  };

  for (int ks = 0; ks < 16; ks++) {
    stage(ks);
    __syncthreads();
    #pragma unroll
    for (int kk2 = 0; kk2 < 2; kk2++) {
      bf16x8 af[4], bfr[4];
      #pragma unroll
      for (int mi = 0; mi < 4; mi++) {
        int row = wm + mi * 16 + c;
        af[mi] = *reinterpret_cast<const bf16x8*>(&lA[row * 64 + (((kk2 * 4 + g) ^ (c & 7)) * 8)]);
      }
      #pragma unroll
      for (int ni = 0; ni < 4; ni++) {
        int row = wn + ni * 16 + c;
        bfr[ni] = *reinterpret_cast<const bf16x8*>(&lB[row * 64 + (((kk2 * 4 + g) ^ (c & 7)) * 8)]);
      }
      #pragma unroll
      for (int mi = 0; mi < 4; mi++)
        #pragma unroll
        for (int ni = 0; ni < 4; ni++)
          acc[mi][ni] = __builtin_amdgcn_mfma_f32_16x16x32_bf16(af[mi], bfr[ni], acc[mi][ni], 0, 0, 0);
    }
    __syncthreads();
  }

  // ---- epilogue via LDS bounce (seg uniform per block) ----
  const int seg = n0 >> 10;
  const float* bp = (seg == 0) ? bq : (seg == 1) ? bk : bv;
  const float sc = (seg == 0) ? qscale : 1.0f;
  ushort* lC = &lS[0][0];                    // 128*128 ushorts = 32KB

  if (seg < 2) {
    // row-major [row][col]: write quadrant, then 16B coalesced stores
    #pragma unroll
    for (int mi = 0; mi < 4; mi++) {
      #pragma unroll
      for (int ni = 0; ni < 4; ni++) {
        int col = wn + ni * 16 + c;
        float bvv = bp[(n0 + col) & 1023];
        #pragma unroll
        for (int j = 0; j < 4; j++) {
          int row = wm + mi * 16 + g * 4 + j;
          lC[row * 128 + col] = f2bf((acc[mi][ni][j] + bvv) * sc);
        }
      }
    }
    __syncthreads();
    ushort* op = (seg == 0) ? Qo : Ko;
    const int b = m0 >> 11, s0r = m0 & 2047;
    #pragma unroll
    for (int i = 0; i < 8; i++) {
      int id = i * 256 + t;
      int row = id >> 4, colblk = id & 15;   // 16 lanes -> same row, 128 cols
      ushort4 v0 = *reinterpret_cast<const ushort4*>(&lC[row * 128 + colblk * 8]);
      ushort4 v1 = *reinterpret_cast<const ushort4*>(&lC[row * 128 + colblk * 8 + 4]);
      int colq = (n0 + colblk * 8) & 1023;
      int h = colq >> 6, dkb = colq & 63;
      ushort* dst = &op[(((size_t)(b * HH + h) * SS + s0r + row) << 6) + dkb];
      reinterpret_cast<ushort4*>(dst)[0] = v0;
      reinterpret_cast<ushort4*>(dst)[1] = v1;
    }
  } else {
    // V: transposed [col][row] so s is contiguous on the read side
    #pragma unroll
    for (int mi = 0; mi < 4; mi++) {
      #pragma unroll
      for (int ni = 0; ni < 4; ni++) {
        int col = wn + ni * 16 + c;
        float bvv = bp[(n0 + col) & 1023];
        int rowbase = wm + mi * 16 + g * 4;
        ushort4 pk;
        pk.x = f2bf(acc[mi][ni][0] + bvv);
        pk.y = f2bf(acc[mi][ni][1] + bvv);
        pk.z = f2bf(acc[mi][ni][2] + bvv);
        pk.w = f2bf(acc[mi][ni][3] + bvv);
        *reinterpret_cast<ushort4*>(&lC[col * 128 + rowbase]) = pk;
      }
    }
    __syncthreads();
    const int b = m0 >> 11, s0r = m0 & 2047;
    #pragma unroll
    for (int i = 0; i < 8; i++) {
      int id = i * 256 + t;
      int col = id >> 4, rowblk = id & 15;   // 16 lanes -> same col, 128 rows (s)
      ushort4 v0 = *reinterpret_cast<const ushort4*>(&lC[col * 128 + rowblk * 8]);
      ushort4 v1 = *reinterpret_cast<const ushort4*>(&lC[col * 128 + rowblk * 8 + 4]);
      int colq = (n0 + col) & 1023;
      int h = colq >> 6, dk = colq & 63;
      ushort* dst = &Vo[(((size_t)(b * HH + h) * DK + dk) << 11) + s0r + rowblk * 8];
      reinterpret_cast<ushort4*>(dst)[0] = v0;
      reinterpret_cast<ushort4*>(dst)[1] = v1;
    }
  }
}

// ---------------- output GEMM: 64x64 tile, grid 1024 = 4 blocks/CU ----------
__global__ __launch_bounds__(256, 4) void gemm_out(const ushort* __restrict__ A,
                                                   const ushort* __restrict__ W,
                                                   const float* __restrict__ bias,
                                                   float* __restrict__ out) {
  constexpr int K = 1024;
  __shared__ __align__(16) ushort lA[64 * 64];
  __shared__ __align__(16) ushort lB[64 * 64];
  const int t = threadIdx.x;
  const int w = t >> 6, lane = t & 63;
  const int flat = blockIdx.x + 16 * blockIdx.y;
  const int xcd = flat & 7, idx = flat >> 3;
  const int m0 = ((xcd << 3) + (idx & 7)) * 64;
  const int n0 = (idx >> 3) * 64;
  const int wm = (w >> 1) * 32, wn = (w & 1) * 32;
  const int c = lane & 15, g = lane >> 4;

  f32x4 acc[2][2];
  #pragma unroll
  for (int i = 0; i < 2; i++)
    #pragma unroll
    for (int j = 0; j < 2; j++) acc[i][j] = f32x4{0.f, 0.f, 0.f, 0.f};

  auto stage = [&](int ks) {
    const int k0 = ks * 64;
    #pragma unroll
    for (int i = 0; i < 2; i++) {
      int ch = i * 256 + t;
      int row = ch >> 3;
      int cs = (ch & 7) ^ (row & 7);
      gl_lds16(&A[(size_t)(m0 + row) * K + k0 + cs * 8], &lA[(i * 256 + w * 64) * 8]);
      gl_lds16(&W[(size_t)(n0 + row) * K + k0 + cs * 8], &lB[(i * 256 + w * 64) * 8]);
    }
  };

  for (int ks = 0; ks < 16; ks++) {
    stage(ks);
    __syncthreads();
    #pragma unroll
    for (int kk2 = 0; kk2 < 2; kk2++) {
      bf16x8 af[2], bfr[2];
      #pragma unroll
      for (int mi = 0; mi < 2; mi++) {
        int row = wm + mi * 16 + c;
        af[mi] = *reinterpret_cast<const bf16x8*>(&lA[row * 64 + (((kk2 * 4 + g) ^ (c & 7)) * 8)]);
      }
      #pragma unroll
      for (int ni = 0; ni < 2; ni++) {
        int row = wn + ni * 16 + c;
        bfr[ni] = *reinterpret_cast<const bf16x8*>(&lB[row * 64 + (((kk2 * 4 + g) ^ (c & 7)) * 8)]);
      }
      #pragma unroll
      for (int mi = 0; mi < 2; mi++)
        #pragma unroll
        for (int ni = 0; ni < 2; ni++)
          acc[mi][ni] = __builtin_amdgcn_mfma_f32_16x16x32_bf16(af[mi], bfr[ni], acc[mi][ni], 0, 0, 0);
    }
    __syncthreads();
  }

  #pragma unroll
  for (int mi = 0; mi < 2; mi++) {
    #pragma unroll
    for (int ni = 0; ni < 2; ni++) {
      int colb = n0 + wn + ni * 16 + c;
      float bv = bias[colb];
      #pragma unroll
      for (int j = 0; j < 4; j++) {
        int row = m0 + wm + mi * 16 + g * 4 + j;
        out[(row << 10) + colb] = acc[mi][ni][j] + bv;
      }
    }
  }
}

// ---------------- causal flash attention v13 -------------------------------
// v12 structure, but the two strips' softmax/PV phases are cross-interleaved
// to hide the P LDS round-trip latency:
//   exp2+writeP(A) -> exp2(B, regs) -> PV(A) -> writeP(B) -> PV(B)
// Single P buffer: B's writes are WAR-ordered after A's reads by the in-order
// LDS pipe (same wave, aliasing). No extra LDS or registers.
__global__ __launch_bounds__(256, 2) void attn_fwd(const ushort* __restrict__ Q,
                                                   const ushort* __restrict__ Kk,
                                                   const ushort* __restrict__ Vt,
                                                   ushort* __restrict__ O) {
  __shared__ __align__(16) ushort ldsK[2][2][64 * 64];
  __shared__ __align__(16) ushort ldsV[2][2][64 * 64];
  __shared__ __align__(16) ushort lds_p[4][16 * 72];
  const int t0 = threadIdx.x;
  const int w = t0 >> 6;
  const int lane = t0 & 63;
  const int c = lane & 15, g = lane >> 4;
  const int flat = blockIdx.x + 16 * blockIdx.y;
  const int swz = (flat & 7) * 64 + (flat >> 3);
  const int bx = swz & 15;                   // 0..15
  const int bh = swz >> 4;                   // 0..31
  const int a = bx * 4 + w;                  // 0..63
  const int rb0 = a * 16;                    // strip A rows
  const int rb1 = 2032 - a * 16;             // strip B rows (mirror)
  const int itB = (2111 - 16 * a) >> 6;      // tiles needed by strip B
  const int itMax = (2111 - 64 * bx) >> 6;   // block-uniform tile count
  const int nS = (itMax + 1) >> 1;           // super-tiles (128 kv each)

  const ushort* qbase = Q + (size_t)bh * SS * DK;
  const ushort* kbase = Kk + (size_t)bh * SS * DK;
  const ushort* vbase = Vt + (size_t)bh * DK * SS;

  bf16x8 onesf;
  #pragma unroll
  for (int i = 0; i < 8; i++) onesf[i] = (short)0x3F80;  // bf16 1.0

  bf16x8 qf[2][2];
  qf[0][0] = *reinterpret_cast<const bf16x8*>(&qbase[(rb0 + c) * DK + g * 8]);
  qf[0][1] = *reinterpret_cast<const bf16x8*>(&qbase[(rb0 + c) * DK + 32 + g * 8]);
  qf[1][0] = *reinterpret_cast<const bf16x8*>(&qbase[(rb1 + c) * DK + g * 8]);
  qf[1][1] = *reinterpret_cast<const bf16x8*>(&qbase[(rb1 + c) * DK + 32 + g * 8]);

  f32x4 oacc[2][4], lacc[2];
  #pragma unroll
  for (int f = 0; f < 2; f++) {
    #pragma unroll
    for (int i = 0; i < 4; i++) oacc[f][i] = f32x4{0.f, 0.f, 0.f, 0.f};
    lacc[f] = f32x4{0.f, 0.f, 0.f, 0.f};
  }

  auto stage = [&](int st, int buf) {
    #pragma unroll
    for (int half = 0; half < 2; half++) {
      int tt = 2 * st + half; if (tt > 31) tt = 31;
      const int kv = tt * 64;
      #pragma unroll
      for (int i = 0; i < 2; i++) {
        int ch = w * 128 + i * 64 + lane;
        int row = ch >> 3;
        int cs = (ch & 7) ^ (row & 7);
        gl_lds16(&kbase[(kv + row) * DK + cs * 8], &ldsK[buf][half][(w * 128 + i * 64) * 8]);
        gl_lds16(&vbase[row * SS + kv + cs * 8], &ldsV[buf][half][(w * 128 + i * 64) * 8]);
      }
    }
  };

  stage(0, 0);
  __syncthreads();
  int cur = 0;

  for (int st = 0; st < nS; ++st) {
    if (st + 1 < nS) stage(st + 1, cur ^ 1);
    #pragma unroll
    for (int half = 0; half < 2; half++) {
      const int t = 2 * st + half;
      const int kv = t * 64;
      const bool run = t < itMax;
      const bool actB = run && (t < itB);
      const bool actA = run && (kv < rb0 + 16);
      if (actA || actB) {
        bf16x8 kf[8];
        #pragma unroll
        for (int i = 0; i < 8; i++) {
          int tt = i >> 1, kk2 = i & 1;
          kf[i] = *reinterpret_cast<const bf16x8*>(
              &ldsK[cur][half][(tt * 16 + c) * 64 + (((kk2 * 4 + g) ^ (c & 7)) * 8)]);
        }
        f32x4 s[2][4];
        __builtin_amdgcn_s_setprio(1);
        if (actB) {
          #pragma unroll
          for (int tt = 0; tt < 4; tt++) {
            f32x4 z = {0.f, 0.f, 0.f, 0.f};
            z = __builtin_amdgcn_mfma_f32_16x16x32_bf16(qf[1][0], kf[tt * 2], z, 0, 0, 0);
            s[1][tt] = __builtin_amdgcn_mfma_f32_16x16x32_bf16(qf[1][1], kf[tt * 2 + 1], z, 0, 0, 0);
          }
        }
        if (actA) {
          #pragma unroll
          for (int tt = 0; tt < 4; tt++) {
            f32x4 z = {0.f, 0.f, 0.f, 0.f};
            z = __builtin_amdgcn_mfma_f32_16x16x32_bf16(qf[0][0], kf[tt * 2], z, 0, 0, 0);
            s[0][tt] = __builtin_amdgcn_mfma_f32_16x16x32_bf16(qf[0][1], kf[tt * 2 + 1], z, 0, 0, 0);
          }
        }
        __builtin_amdgcn_s_setprio(0);

        bf16x8 vf[8];
        #pragma unroll
        for (int i = 0; i < 8; i++) {
          int dt = i >> 1, kk2 = i & 1;
          vf[i] = *reinterpret_cast<const bf16x8*>(
              &ldsV[cur][half][(dt * 16 + c) * 64 + (((kk2 * 4 + g) ^ (c & 7)) * 8)]);
        }

        ushort* pb = &lds_p[w][0];

        // ---- phase 1: strip A mask+exp2 -> write P_A ----
        if (actA) {
          const bool edge = (kv + 63 > rb0);
          #pragma unroll
          for (int tt = 0; tt < 4; tt++) {
            int kj = kv + tt * 16 + c;
            #pragma unroll
            for (int j = 0; j < 4; j++) {
              float p = exp2_hw(s[0][tt][j]);
              if (edge && kj > rb0 + g * 4 + j) p = 0.f;
              pb[(g * 4 + j) * 72 + tt * 16 + c] = f2bf(p);
            }
          }
        }
        // ---- phase 2: strip B mask+exp2 into regs (hides A's write->read) --
        if (actB) {
          const bool edge = (kv + 63 > rb1);
          #pragma unroll
          for (int tt = 0; tt < 4; tt++) {
            int kj = kv + tt * 16 + c;
            #pragma unroll
            for (int j = 0; j < 4; j++) {
              float p = exp2_hw(s[1][tt][j]);
              if (edge && kj > rb1 + g * 4 + j) p = 0.f;
              s[1][tt][j] = p;
            }
          }
        }
        // ---- phase 3: PV A (reads P_A; B's write waits on these reads) ----
        if (actA) {
          __builtin_amdgcn_s_setprio(1);
          #pragma unroll
          for (int kk2 = 0; kk2 < 2; kk2++) {
            bf16x8 pa = *reinterpret_cast<const bf16x8*>(&pb[c * 72 + kk2 * 32 + g * 8]);
            #pragma unroll
            for (int dt = 0; dt < 4; dt++)
              oacc[0][dt] = __builtin_amdgcn_mfma_f32_16x16x32_bf16(pa, vf[dt * 2 + kk2], oacc[0][dt], 0, 0, 0);
            lacc[0] = __builtin_amdgcn_mfma_f32_16x16x32_bf16(pa, onesf, lacc[0], 0, 0, 0);
          }
          __builtin_amdgcn_s_setprio(0);
        }
        // ---- phase 4+5: write P_B (overlaps PV A issue), then PV B ----
        if (actB) {
          #pragma unroll
          for (int tt = 0; tt < 4; tt++) {
            #pragma unroll
            for (int j = 0; j < 4; j++)
              pb[(g * 4 + j) * 72 + tt * 16 + c] = f2bf(s[1][tt][j]);
          }
          __builtin_amdgcn_s_setprio(1);
          #pragma unroll
          for (int kk2 = 0; kk2 < 2; kk2++) {
            bf16x8 pa = *reinterpret_cast<const bf16x8*>(&pb[c * 72 + kk2 * 32 + g * 8]);
            #pragma unroll
            for (int dt = 0; dt < 4; dt++)
              oacc[1][dt] = __builtin_amdgcn_mfma_f32_16x16x32_bf16(pa, vf[dt * 2 + kk2], oacc[1][dt], 0, 0, 0);
            lacc[1] = __builtin_amdgcn_mfma_f32_16x16x32_bf16(pa, onesf, lacc[1], 0, 0, 0);
          }
          __builtin_amdgcn_s_setprio(0);
        }
      }
    }
    __syncthreads();
    cur ^= 1;
  }

  const int b = bh >> 4, h = bh & 15;
  #pragma unroll
  for (int f = 0; f < 2; f++) {
    const int rbf = (f == 0) ? rb0 : rb1;
    #pragma unroll
    for (int j = 0; j < 4; j++) {
      float linv = 1.0f / lacc[f][j];
      int row = rbf + g * 4 + j;
      #pragma unroll
      for (int dt = 0; dt < 4; dt++) {
        float val = oacc[f][dt][j] * linv;
        O[((size_t)(b * SS + row) << 10) + h * DK + dt * 16 + c] = f2bf(val);
      }
    }
  }
}

// ---------------- launch ----------------
extern "C" void kernel_launch(void* const* d_in, const int* in_sizes, int n_in,
                              void* d_out, int out_size, void* d_ws, size_t ws_size,
                              hipStream_t stream) {
  const float* x  = (const float*)d_in[0];
  const float* wq = (const float*)d_in[2];
  const float* bq = (const float*)d_in[3];
  const float* wk = (const float*)d_in[4];
  const float* bk = (const float*)d_in[5];
  const float* wv = (const float*)d_in[6];
  const float* bv = (const float*)d_in[7];
  const float* wo = (const float*)d_in[8];
  const float* bo = (const float*)d_in[9];

  ushort* ws = (ushort*)d_ws;
  ushort* xb   = ws;                          // 4M bf16 (x); reused as attn out
  ushort* wqkv = xb + (size_t)MM * DD;        // 3M bf16 (wq|wk|wv)

  const float qscale = 0.18033688011112043f;  // (1/8) * log2(e)
  const size_t needA = (size_t)(4 + 4 + 4 * 4) * DD * DD * sizeof(ushort);  // 40MB layout

  if (ws_size >= needA) {
    // layout A: xb | wqkv | wo | q | k | v  -- single fused cvt, 4 kernels total
    ushort* wob = wqkv + (size_t)3 * DD * DD;
    ushort* qw  = wob + (size_t)DD * DD;
    ushort* kw  = qw + (size_t)MM * DD;
    ushort* vw  = kw + (size_t)MM * DD;
    cvt5_f32_bf16<<<2048, 256, 0, stream>>>(x, wq, wk, wv, wo, xb, wqkv);
    gemm_qkv<<<dim3(24, 32), 256, 0, stream>>>(xb, wqkv, bq, bk, bv, qw, kw, vw, qscale);
    attn_fwd<<<dim3(16, BB * HH), 256, 0, stream>>>(qw, kw, vw, xb);
    gemm_out<<<dim3(16, 64), 256, 0, stream>>>(xb, wob, bo, (float*)d_out);
  } else {
    // layout B fallback: wo reuses wqkv slot after gemm_qkv
    ushort* qw = wqkv + (size_t)3 * DD * DD;
    ushort* kw = qw + (size_t)MM * DD;
    ushort* vw = kw + (size_t)MM * DD;
    cvt_f32_bf16<<<2048, 256, 0, stream>>>(x, xb, MM * DD / 4);
    cvt3_f32_bf16<<<1536, 256, 0, stream>>>(wq, wk, wv, wqkv);
    gemm_qkv<<<dim3(24, 32), 256, 0, stream>>>(xb, wqkv, bq, bk, bv, qw, kw, vw, qscale);
    cvt_f32_bf16<<<512, 256, 0, stream>>>(wo, wqkv, DD * DD / 4);
    attn_fwd<<<dim3(16, BB * HH), 256, 0, stream>>>(qw, kw, vw, xb);
    gemm_out<<<dim3(16, 64), 256, 0, stream>>>(xb, wqkv, bo, (float*)d_out);
  }
}

// Round 18
// 95.829 us; speedup vs baseline: 1.0281x; 1.0281x over previous
//
#include <hip/hip_runtime.h>
#include <hip/hip_bf16.h>

#define BB 2
#define SS 2048
#define DD 1024
#define HH 16
#define DK 64
#define MM (BB*SS)   // 4096

typedef __attribute__((ext_vector_type(8))) short bf16x8;
typedef __attribute__((ext_vector_type(4))) float f32x4;

__device__ inline ushort f2bf(float f) {
  __hip_bfloat16 h = __float2bfloat16(f);
  return *reinterpret_cast<ushort*>(&h);
}

// hardware exp2 (single v_exp_f32)
__device__ __forceinline__ float exp2_hw(float x) {
  float r; asm("v_exp_f32 %0, %1" : "=v"(r) : "v"(x)); return r;
}

// async global->LDS, 16B per lane. ldst must be wave-uniform; HW adds lane*16.
__device__ __forceinline__ void gl_lds16(const ushort* g, ushort* l) {
  __builtin_amdgcn_global_load_lds((const __attribute__((address_space(1))) void*)g,
                                   (__attribute__((address_space(3))) void*)l, 16, 0, 0);
}

// ---------------- fp32 -> bf16 convert (float4 vectorized) ----------------
__global__ void cvt_f32_bf16(const float* __restrict__ src, ushort* __restrict__ dst, int n4) {
  int i = blockIdx.x * blockDim.x + threadIdx.x;
  int stride = gridDim.x * blockDim.x;
  for (int idx = i; idx < n4; idx += stride) {
    float4 v = reinterpret_cast<const float4*>(src)[idx];
    ushort4 o;
    o.x = f2bf(v.x); o.y = f2bf(v.y); o.z = f2bf(v.z); o.w = f2bf(v.w);
    reinterpret_cast<ushort4*>(dst)[idx] = o;
  }
}

// convert 3 weight matrices into one contiguous bf16 buffer
__global__ void cvt3_f32_bf16(const float* __restrict__ s0, const float* __restrict__ s1,
                              const float* __restrict__ s2, ushort* __restrict__ dst) {
  const int n4seg = DD * DD / 4;
  int i = blockIdx.x * blockDim.x + threadIdx.x;
  int stride = gridDim.x * blockDim.x;
  for (int idx = i; idx < 3 * n4seg; idx += stride) {
    int seg = idx / n4seg;
    int off = idx - seg * n4seg;
    const float* s = (seg == 0) ? s0 : (seg == 1) ? s1 : s2;
    float4 v = reinterpret_cast<const float4*>(s)[off];
    ushort4 o;
    o.x = f2bf(v.x); o.y = f2bf(v.y); o.z = f2bf(v.z); o.w = f2bf(v.w);
    reinterpret_cast<ushort4*>(dst)[idx] = o;
  }
}

// one-shot convert: x (MM*DD) -> dx ; wq|wk|wv|wo (4*DD*DD) -> dw contiguous
__global__ void cvt5_f32_bf16(const float* __restrict__ x,
                              const float* __restrict__ s0, const float* __restrict__ s1,
                              const float* __restrict__ s2, const float* __restrict__ s3,
                              ushort* __restrict__ dx, ushort* __restrict__ dw) {
  const int n4x = MM * DD / 4;       // 1M float4
  const int n4seg = DD * DD / 4;     // 256K float4 per weight
  const int total = n4x + 4 * n4seg; // 2M float4
  int i = blockIdx.x * blockDim.x + threadIdx.x;
  int stride = gridDim.x * blockDim.x;
  for (int idx = i; idx < total; idx += stride) {
    float4 v; ushort4* outp;
    if (idx < n4x) {
      v = reinterpret_cast<const float4*>(x)[idx];
      outp = &reinterpret_cast<ushort4*>(dx)[idx];
    } else {
      int widx = idx - n4x;
      int seg = widx / n4seg;
      int off = widx - seg * n4seg;
      const float* s = (seg == 0) ? s0 : (seg == 1) ? s1 : (seg == 2) ? s2 : s3;
      v = reinterpret_cast<const float4*>(s)[off];
      outp = &reinterpret_cast<ushort4*>(dw)[widx];
    }
    ushort4 o;
    o.x = f2bf(v.x); o.y = f2bf(v.y); o.z = f2bf(v.z); o.w = f2bf(v.w);
    *outp = o;
  }
}

// ---------------- fused QKV GEMM: [4096,1024] x [3072,1024]^T ----------------
// 128x128 tile, BK=64, single-buffered 32KB LDS (m97 structure), 3 blocks/CU.
// Epilogue bounces C through the (then-dead) staging LDS for coalesced 16B
// stores: Q/K row-major [row][col]; V transposed [col][row] (s contiguous).
__global__ __launch_bounds__(256, 3) void gemm_qkv(const ushort* __restrict__ A,
                                                   const ushort* __restrict__ Wqkv,
                                                   const float* __restrict__ bq,
                                                   const float* __restrict__ bk,
                                                   const float* __restrict__ bv,
                                                   ushort* __restrict__ Qo,
                                                   ushort* __restrict__ Ko,
                                                   ushort* __restrict__ Vo,
                                                   float qscale) {
  constexpr int K = 1024;
  __shared__ __align__(16) ushort lS[2][128 * 64];   // staging; reused as C-tile
  ushort* lA = lS[0];
  ushort* lB = lS[1];
  const int t = threadIdx.x;
  const int w = t >> 6, lane = t & 63;
  const int flat = blockIdx.x + 24 * blockIdx.y;
  const int xcd = flat & 7, idx = flat >> 3;
  const int m0 = ((xcd << 2) + (idx & 3)) * 128;
  const int n0 = (idx >> 2) * 128;
  const int wm = (w >> 1) * 64, wn = (w & 1) * 64;
  const int c = lane & 15, g = lane >> 4;

  f32x4 acc[4][4];
  #pragma unroll
  for (int i = 0; i < 4; i++)
    #pragma unroll
    for (int j = 0; j < 4; j++) acc[i][j] = f32x4{0.f, 0.f, 0.f, 0.f};

  auto stage = [&](int ks) {
    const int k0 = ks * 64;
    #pragma unroll
    for (int i = 0; i < 4; i++) {
      int ch = w * 256 + i * 64 + lane;
      int row = ch >> 3;
      int cs = (ch & 7) ^ (row & 7);
      gl_lds16(&A[(size_t)(m0 + row) * K + k0 + cs * 8], &lA[(w * 256 + i * 64) * 8]);
      gl_lds16(&Wqkv[(size_t)(n0 + row) * K + k0 + cs * 8], &lB[(w * 256 + i * 64) * 8]);
    }
  };

  for (int ks = 0; ks < 16; ks++) {
    stage(ks);
    __syncthreads();
    #pragma unroll
    for (int kk2 = 0; kk2 < 2; kk2++) {
      bf16x8 af[4], bfr[4];
      #pragma unroll
      for (int mi = 0; mi < 4; mi++) {
        int row = wm + mi * 16 + c;
        af[mi] = *reinterpret_cast<const bf16x8*>(&lA[row * 64 + (((kk2 * 4 + g) ^ (c & 7)) * 8)]);
      }
      #pragma unroll
      for (int ni = 0; ni < 4; ni++) {
        int row = wn + ni * 16 + c;
        bfr[ni] = *reinterpret_cast<const bf16x8*>(&lB[row * 64 + (((kk2 * 4 + g) ^ (c & 7)) * 8)]);
      }
      #pragma unroll
      for (int mi = 0; mi < 4; mi++)
        #pragma unroll
        for (int ni = 0; ni < 4; ni++)
          acc[mi][ni] = __builtin_amdgcn_mfma_f32_16x16x32_bf16(af[mi], bfr[ni], acc[mi][ni], 0, 0, 0);
    }
    __syncthreads();
  }

  // ---- epilogue via LDS bounce (seg uniform per block) ----
  const int seg = n0 >> 10;
  const float* bp = (seg == 0) ? bq : (seg == 1) ? bk : bv;
  const float sc = (seg == 0) ? qscale : 1.0f;
  ushort* lC = &lS[0][0];                    // 128*128 ushorts = 32KB

  if (seg < 2) {
    // row-major [row][col]: write quadrant, then 16B coalesced stores
    #pragma unroll
    for (int mi = 0; mi < 4; mi++) {
      #pragma unroll
      for (int ni = 0; ni < 4; ni++) {
        int col = wn + ni * 16 + c;
        float bvv = bp[(n0 + col) & 1023];
        #pragma unroll
        for (int j = 0; j < 4; j++) {
          int row = wm + mi * 16 + g * 4 + j;
          lC[row * 128 + col] = f2bf((acc[mi][ni][j] + bvv) * sc);
        }
      }
    }
    __syncthreads();
    ushort* op = (seg == 0) ? Qo : Ko;
    const int b = m0 >> 11, s0r = m0 & 2047;
    #pragma unroll
    for (int i = 0; i < 8; i++) {
      int id = i * 256 + t;
      int row = id >> 4, colblk = id & 15;   // 16 lanes -> same row, 128 cols
      ushort4 v0 = *reinterpret_cast<const ushort4*>(&lC[row * 128 + colblk * 8]);
      ushort4 v1 = *reinterpret_cast<const ushort4*>(&lC[row * 128 + colblk * 8 + 4]);
      int colq = (n0 + colblk * 8) & 1023;
      int h = colq >> 6, dkb = colq & 63;
      ushort* dst = &op[(((size_t)(b * HH + h) * SS + s0r + row) << 6) + dkb];
      reinterpret_cast<ushort4*>(dst)[0] = v0;
      reinterpret_cast<ushort4*>(dst)[1] = v1;
    }
  } else {
    // V: transposed [col][row] so s is contiguous on the read side
    #pragma unroll
    for (int mi = 0; mi < 4; mi++) {
      #pragma unroll
      for (int ni = 0; ni < 4; ni++) {
        int col = wn + ni * 16 + c;
        float bvv = bp[(n0 + col) & 1023];
        int rowbase = wm + mi * 16 + g * 4;
        ushort4 pk;
        pk.x = f2bf(acc[mi][ni][0] + bvv);
        pk.y = f2bf(acc[mi][ni][1] + bvv);
        pk.z = f2bf(acc[mi][ni][2] + bvv);
        pk.w = f2bf(acc[mi][ni][3] + bvv);
        *reinterpret_cast<ushort4*>(&lC[col * 128 + rowbase]) = pk;
      }
    }
    __syncthreads();
    const int b = m0 >> 11, s0r = m0 & 2047;
    #pragma unroll
    for (int i = 0; i < 8; i++) {
      int id = i * 256 + t;
      int col = id >> 4, rowblk = id & 15;   // 16 lanes -> same col, 128 rows (s)
      ushort4 v0 = *reinterpret_cast<const ushort4*>(&lC[col * 128 + rowblk * 8]);
      ushort4 v1 = *reinterpret_cast<const ushort4*>(&lC[col * 128 + rowblk * 8 + 4]);
      int colq = (n0 + col) & 1023;
      int h = colq >> 6, dk = colq & 63;
      ushort* dst = &Vo[(((size_t)(b * HH + h) * DK + dk) << 11) + s0r + rowblk * 8];
      reinterpret_cast<ushort4*>(dst)[0] = v0;
      reinterpret_cast<ushort4*>(dst)[1] = v1;
    }
  }
}

// ---------------- output GEMM: 64x64 tile, grid 1024 = 4 blocks/CU ----------
__global__ __launch_bounds__(256, 4) void gemm_out(const ushort* __restrict__ A,
                                                   const ushort* __restrict__ W,
                                                   const float* __restrict__ bias,
                                                   float* __restrict__ out) {
  constexpr int K = 1024;
  __shared__ __align__(16) ushort lA[64 * 64];
  __shared__ __align__(16) ushort lB[64 * 64];
  const int t = threadIdx.x;
  const int w = t >> 6, lane = t & 63;
  const int flat = blockIdx.x + 16 * blockIdx.y;
  const int xcd = flat & 7, idx = flat >> 3;
  const int m0 = ((xcd << 3) + (idx & 7)) * 64;
  const int n0 = (idx >> 3) * 64;
  const int wm = (w >> 1) * 32, wn = (w & 1) * 32;
  const int c = lane & 15, g = lane >> 4;

  f32x4 acc[2][2];
  #pragma unroll
  for (int i = 0; i < 2; i++)
    #pragma unroll
    for (int j = 0; j < 2; j++) acc[i][j] = f32x4{0.f, 0.f, 0.f, 0.f};

  auto stage = [&](int ks) {
    const int k0 = ks * 64;
    #pragma unroll
    for (int i = 0; i < 2; i++) {
      int ch = i * 256 + t;
      int row = ch >> 3;
      int cs = (ch & 7) ^ (row & 7);
      gl_lds16(&A[(size_t)(m0 + row) * K + k0 + cs * 8], &lA[(i * 256 + w * 64) * 8]);
      gl_lds16(&W[(size_t)(n0 + row) * K + k0 + cs * 8], &lB[(i * 256 + w * 64) * 8]);
    }
  };

  for (int ks = 0; ks < 16; ks++) {
    stage(ks);
    __syncthreads();
    #pragma unroll
    for (int kk2 = 0; kk2 < 2; kk2++) {
      bf16x8 af[2], bfr[2];
      #pragma unroll
      for (int mi = 0; mi < 2; mi++) {
        int row = wm + mi * 16 + c;
        af[mi] = *reinterpret_cast<const bf16x8*>(&lA[row * 64 + (((kk2 * 4 + g) ^ (c & 7)) * 8)]);
      }
      #pragma unroll
      for (int ni = 0; ni < 2; ni++) {
        int row = wn + ni * 16 + c;
        bfr[ni] = *reinterpret_cast<const bf16x8*>(&lB[row * 64 + (((kk2 * 4 + g) ^ (c & 7)) * 8)]);
      }
      #pragma unroll
      for (int mi = 0; mi < 2; mi++)
        #pragma unroll
        for (int ni = 0; ni < 2; ni++)
          acc[mi][ni] = __builtin_amdgcn_mfma_f32_16x16x32_bf16(af[mi], bfr[ni], acc[mi][ni], 0, 0, 0);
    }
    __syncthreads();
  }

  #pragma unroll
  for (int mi = 0; mi < 2; mi++) {
    #pragma unroll
    for (int ni = 0; ni < 2; ni++) {
      int colb = n0 + wn + ni * 16 + c;
      float bv = bias[colb];
      #pragma unroll
      for (int j = 0; j < 4; j++) {
        int row = m0 + wm + mi * 16 + g * 4 + j;
        out[(row << 10) + colb] = acc[mi][ni][j] + bv;
      }
    }
  }
}

// ---------------- causal flash attention v14 -------------------------------
// = round-16 verified v12 structure (mirror-paired strips, 128-kv super-tiles,
// quad-buffer K/V, zero-shift exp2 softmax, l via ones-MFMA, P pitch 72)
// + CU-pairing fix: blocks flat and flat+256 co-reside on a CU; complement
// bx on bit5 of swz so paired blocks have complementary tile counts
// (32-bx) + (32-(15-bx)) = 49 uniform (was: same bx -> up to 64 vs 34).
__global__ __launch_bounds__(256, 2) void attn_fwd(const ushort* __restrict__ Q,
                                                   const ushort* __restrict__ Kk,
                                                   const ushort* __restrict__ Vt,
                                                   ushort* __restrict__ O) {
  __shared__ __align__(16) ushort ldsK[2][2][64 * 64];
  __shared__ __align__(16) ushort ldsV[2][2][64 * 64];
  __shared__ __align__(16) ushort lds_p[4][16 * 72];
  const int t0 = threadIdx.x;
  const int w = t0 >> 6;
  const int lane = t0 & 63;
  const int c = lane & 15, g = lane >> 4;
  const int flat = blockIdx.x + 16 * blockIdx.y;
  const int swz = (flat & 7) * 64 + (flat >> 3);
  const int bx = (swz & 15) ^ (15 * ((swz >> 5) & 1));  // CU-pair complement
  const int bh = swz >> 4;                   // 0..31
  const int a = bx * 4 + w;                  // 0..63
  const int rb0 = a * 16;                    // strip A rows
  const int rb1 = 2032 - a * 16;             // strip B rows (mirror)
  const int itB = (2111 - 16 * a) >> 6;      // tiles needed by strip B
  const int itMax = (2111 - 64 * bx) >> 6;   // block-uniform tile count
  const int nS = (itMax + 1) >> 1;           // super-tiles (128 kv each)

  const ushort* qbase = Q + (size_t)bh * SS * DK;
  const ushort* kbase = Kk + (size_t)bh * SS * DK;
  const ushort* vbase = Vt + (size_t)bh * DK * SS;

  bf16x8 onesf;
  #pragma unroll
  for (int i = 0; i < 8; i++) onesf[i] = (short)0x3F80;  // bf16 1.0

  bf16x8 qf[2][2];
  qf[0][0] = *reinterpret_cast<const bf16x8*>(&qbase[(rb0 + c) * DK + g * 8]);
  qf[0][1] = *reinterpret_cast<const bf16x8*>(&qbase[(rb0 + c) * DK + 32 + g * 8]);
  qf[1][0] = *reinterpret_cast<const bf16x8*>(&qbase[(rb1 + c) * DK + g * 8]);
  qf[1][1] = *reinterpret_cast<const bf16x8*>(&qbase[(rb1 + c) * DK + 32 + g * 8]);

  f32x4 oacc[2][4], lacc[2];
  #pragma unroll
  for (int f = 0; f < 2; f++) {
    #pragma unroll
    for (int i = 0; i < 4; i++) oacc[f][i] = f32x4{0.f, 0.f, 0.f, 0.f};
    lacc[f] = f32x4{0.f, 0.f, 0.f, 0.f};
  }

  auto stage = [&](int st, int buf) {
    #pragma unroll
    for (int half = 0; half < 2; half++) {
      int tt = 2 * st + half; if (tt > 31) tt = 31;
      const int kv = tt * 64;
      #pragma unroll
      for (int i = 0; i < 2; i++) {
        int ch = w * 128 + i * 64 + lane;
        int row = ch >> 3;
        int cs = (ch & 7) ^ (row & 7);
        gl_lds16(&kbase[(kv + row) * DK + cs * 8], &ldsK[buf][half][(w * 128 + i * 64) * 8]);
        gl_lds16(&vbase[row * SS + kv + cs * 8], &ldsV[buf][half][(w * 128 + i * 64) * 8]);
      }
    }
  };

  stage(0, 0);
  __syncthreads();
  int cur = 0;

  for (int st = 0; st < nS; ++st) {
    if (st + 1 < nS) stage(st + 1, cur ^ 1);
    #pragma unroll
    for (int half = 0; half < 2; half++) {
      const int t = 2 * st + half;
      const int kv = t * 64;
      const bool run = t < itMax;
      const bool actB = run && (t < itB);
      const bool actA = run && (kv < rb0 + 16);
      if (actA || actB) {
        bf16x8 kf[8];
        #pragma unroll
        for (int i = 0; i < 8; i++) {
          int tt = i >> 1, kk2 = i & 1;
          kf[i] = *reinterpret_cast<const bf16x8*>(
              &ldsK[cur][half][(tt * 16 + c) * 64 + (((kk2 * 4 + g) ^ (c & 7)) * 8)]);
        }
        f32x4 s[2][4];
        __builtin_amdgcn_s_setprio(1);
        if (actB) {
          #pragma unroll
          for (int tt = 0; tt < 4; tt++) {
            f32x4 z = {0.f, 0.f, 0.f, 0.f};
            z = __builtin_amdgcn_mfma_f32_16x16x32_bf16(qf[1][0], kf[tt * 2], z, 0, 0, 0);
            s[1][tt] = __builtin_amdgcn_mfma_f32_16x16x32_bf16(qf[1][1], kf[tt * 2 + 1], z, 0, 0, 0);
          }
        }
        if (actA) {
          #pragma unroll
          for (int tt = 0; tt < 4; tt++) {
            f32x4 z = {0.f, 0.f, 0.f, 0.f};
            z = __builtin_amdgcn_mfma_f32_16x16x32_bf16(qf[0][0], kf[tt * 2], z, 0, 0, 0);
            s[0][tt] = __builtin_amdgcn_mfma_f32_16x16x32_bf16(qf[0][1], kf[tt * 2 + 1], z, 0, 0, 0);
          }
        }
        __builtin_amdgcn_s_setprio(0);

        bf16x8 vf[8];
        #pragma unroll
        for (int i = 0; i < 8; i++) {
          int dt = i >> 1, kk2 = i & 1;
          vf[i] = *reinterpret_cast<const bf16x8*>(
              &ldsV[cur][half][(dt * 16 + c) * 64 + (((kk2 * 4 + g) ^ (c & 7)) * 8)]);
        }

        #pragma unroll
        for (int f = 0; f < 2; f++) {
          const bool act = (f == 0) ? actA : actB;
          if (act) {
            const int rbf = (f == 0) ? rb0 : rb1;
            ushort* pb = &lds_p[w][0];
            const bool edge = (kv + 63 > rbf);
            #pragma unroll
            for (int tt = 0; tt < 4; tt++) {
              int kj = kv + tt * 16 + c;
              #pragma unroll
              for (int j = 0; j < 4; j++) {
                float p = exp2_hw(s[f][tt][j]);
                if (edge && kj > rbf + g * 4 + j) p = 0.f;
                pb[(g * 4 + j) * 72 + tt * 16 + c] = f2bf(p);
              }
            }
            __builtin_amdgcn_s_setprio(1);
            #pragma unroll
            for (int kk2 = 0; kk2 < 2; kk2++) {
              bf16x8 pa = *reinterpret_cast<const bf16x8*>(&pb[c * 72 + kk2 * 32 + g * 8]);
              #pragma unroll
              for (int dt = 0; dt < 4; dt++)
                oacc[f][dt] = __builtin_amdgcn_mfma_f32_16x16x32_bf16(pa, vf[dt * 2 + kk2], oacc[f][dt], 0, 0, 0);
              lacc[f] = __builtin_amdgcn_mfma_f32_16x16x32_bf16(pa, onesf, lacc[f], 0, 0, 0);
            }
            __builtin_amdgcn_s_setprio(0);
          }
        }
      }
    }
    __syncthreads();
    cur ^= 1;
  }

  const int b = bh >> 4, h = bh & 15;
  #pragma unroll
  for (int f = 0; f < 2; f++) {
    const int rbf = (f == 0) ? rb0 : rb1;
    #pragma unroll
    for (int j = 0; j < 4; j++) {
      float linv = 1.0f / lacc[f][j];
      int row = rbf + g * 4 + j;
      #pragma unroll
      for (int dt = 0; dt < 4; dt++) {
        float val = oacc[f][dt][j] * linv;
        O[((size_t)(b * SS + row) << 10) + h * DK + dt * 16 + c] = f2bf(val);
      }
    }
  }
}

// ---------------- launch ----------------
extern "C" void kernel_launch(void* const* d_in, const int* in_sizes, int n_in,
                              void* d_out, int out_size, void* d_ws, size_t ws_size,
                              hipStream_t stream) {
  const float* x  = (const float*)d_in[0];
  const float* wq = (const float*)d_in[2];
  const float* bq = (const float*)d_in[3];
  const float* wk = (const float*)d_in[4];
  const float* bk = (const float*)d_in[5];
  const float* wv = (const float*)d_in[6];
  const float* bv = (const float*)d_in[7];
  const float* wo = (const float*)d_in[8];
  const float* bo = (const float*)d_in[9];

  ushort* ws = (ushort*)d_ws;
  ushort* xb   = ws;                          // 4M bf16 (x); reused as attn out
  ushort* wqkv = xb + (size_t)MM * DD;        // 3M bf16 (wq|wk|wv)

  const float qscale = 0.18033688011112043f;  // (1/8) * log2(e)
  const size_t needA = (size_t)(4 + 4 + 4 * 4) * DD * DD * sizeof(ushort);  // 40MB layout

  if (ws_size >= needA) {
    // layout A: xb | wqkv | wo | q | k | v  -- single fused cvt, 4 kernels total
    ushort* wob = wqkv + (size_t)3 * DD * DD;
    ushort* qw  = wob + (size_t)DD * DD;
    ushort* kw  = qw + (size_t)MM * DD;
    ushort* vw  = kw + (size_t)MM * DD;
    cvt5_f32_bf16<<<2048, 256, 0, stream>>>(x, wq, wk, wv, wo, xb, wqkv);
    gemm_qkv<<<dim3(24, 32), 256, 0, stream>>>(xb, wqkv, bq, bk, bv, qw, kw, vw, qscale);
    attn_fwd<<<dim3(16, BB * HH), 256, 0, stream>>>(qw, kw, vw, xb);
    gemm_out<<<dim3(16, 64), 256, 0, stream>>>(xb, wob, bo, (float*)d_out);
  } else {
    // layout B fallback: wo reuses wqkv slot after gemm_qkv
    ushort* qw = wqkv + (size_t)3 * DD * DD;
    ushort* kw = qw + (size_t)MM * DD;
    ushort* vw = kw + (size_t)MM * DD;
    cvt_f32_bf16<<<2048, 256, 0, stream>>>(x, xb, MM * DD / 4);
    cvt3_f32_bf16<<<1536, 256, 0, stream>>>(wq, wk, wv, wqkv);
    gemm_qkv<<<dim3(24, 32), 256, 0, stream>>>(xb, wqkv, bq, bk, bv, qw, kw, vw, qscale);
    cvt_f32_bf16<<<512, 256, 0, stream>>>(wo, wqkv, DD * DD / 4);
    attn_fwd<<<dim3(16, BB * HH), 256, 0, stream>>>(qw, kw, vw, xb);
    gemm_out<<<dim3(16, 64), 256, 0, stream>>>(xb, wqkv, bo, (float*)d_out);
  }
}